// Round 8
// baseline (825.404 us; speedup 1.0000x reference)
//
#include <hip/hip_runtime.h>
#include <math.h>

#define B_ 8
#define L_ 4096
#define H_ 32
#define D_ 128
#define HID_ 4096
#define INTER_ 11008
#define EPS_ 1e-6f
#define NP_ 8          // attention partitions over L (R5 proven)
#define PSTRIDE_ 136   // floats per attention partial: 128 acc + m + l + pad

typedef float f4v __attribute__((ext_vector_type(4)));

__device__ __forceinline__ float dot4v(f4v a, f4v b) {
  f4v t = a * b;
  return t.x + t.y + t.z + t.w;
}
__device__ __forceinline__ float wave_sum(float v) {
#pragma unroll
  for (int m = 32; m >= 1; m >>= 1) v += __shfl_xor(v, m, 64);
  return v;
}
__device__ __forceinline__ f4v shfl_xor4(f4v v, int mask) {
  f4v r;
  r.x = __shfl_xor(v.x, mask, 64);
  r.y = __shfl_xor(v.y, mask, 64);
  r.z = __shfl_xor(v.z, mask, 64);
  r.w = __shfl_xor(v.w, mask, 64);
  return r;
}

// ---------------- RMSNorm: grid=B, block=1024 (R1/R3 proven) + counter zeroing ----------------
__global__ __launch_bounds__(1024) void rmsnorm_kernel(const float* __restrict__ x,
                                                       const float* __restrict__ w,
                                                       float* __restrict__ out,
                                                       int* __restrict__ counters) {
  int b = blockIdx.x;
  int tid = threadIdx.x;
  if (counters && b == 0 && tid < 256) counters[tid] = 0;  // attn split-K counters
  const float4* xb = (const float4*)(x + (size_t)b * HID_);
  const float4* wp = (const float4*)w;
  float4* ob = (float4*)(out + (size_t)b * HID_);
  float4 v = xb[tid];
  float ss = v.x * v.x + v.y * v.y + v.z * v.z + v.w * v.w;
  ss = wave_sum(ss);
  __shared__ float red[16];
  int wid = tid >> 6, lane = tid & 63;
  if (lane == 0) red[wid] = ss;
  __syncthreads();
  float tot = 0.f;
#pragma unroll
  for (int i = 0; i < 16; i++) tot += red[i];
  float rs = rsqrtf(tot * (1.0f / (float)HID_) + EPS_);
  float4 wv = wp[tid];
  float4 o;
  o.x = v.x * rs * wv.x;
  o.y = v.y * rs * wv.y;
  o.z = v.z * rs * wv.z;
  o.w = v.w * rs * wv.w;
  ob[tid] = o;
}

// ======== GEMV, x staged in LDS (R5 proven, byte-identical structure) ========
template <int KD>
__global__ __launch_bounds__(256) void gemv_lds(const float* __restrict__ W,
                                                const float* __restrict__ x,
                                                const float* __restrict__ res,
                                                float* __restrict__ out, int ostride) {
  constexpr int NF4 = KD / 4;
  constexpr int NCH = (NF4 + 255) / 256;
  int tid = threadIdx.x;
  int wid = tid >> 6, lane = tid & 63;
  int wave = (int)blockIdx.x * 4 + wid;
  int n0 = wave * 2;
  const f4v* w0 = (const f4v*)(W + (size_t)n0 * KD);
  const f4v* w1 = w0 + NF4;
  const f4v* xp = (const f4v*)x;
  __shared__ f4v xs[8][256];
  float acc0[8] = {}, acc1[8] = {};
  for (int ch = 0; ch < NCH; ch++) {
    int base = ch * 256;
    int cnt = NF4 - base;
    if (cnt > 256) cnt = 256;
    if (ch) __syncthreads();  // protect previous chunk reads
    if (tid < cnt) {
#pragma unroll
      for (int i = 0; i < 8; i++) xs[i][tid] = xp[(size_t)i * NF4 + base + tid];
    }
    __syncthreads();
#pragma unroll
    for (int c = 0; c < 4; c++) {
      int r4 = lane + c * 64;
      if (r4 < cnt) {
        f4v a0 = __builtin_nontemporal_load(w0 + base + r4);
        f4v a1 = __builtin_nontemporal_load(w1 + base + r4);
#pragma unroll
        for (int b = 0; b < 8; b++) {
          f4v xv = xs[b][r4];
          acc0[b] += dot4v(a0, xv);
          acc1[b] += dot4v(a1, xv);
        }
      }
    }
  }
#pragma unroll
  for (int b = 0; b < 8; b++) {
    float v0 = wave_sum(acc0[b]);
    float v1 = wave_sum(acc1[b]);
    if (lane == 0) {
      size_t o = (size_t)b * ostride + n0;
      float r0 = res ? res[o] : 0.f;
      float r1 = res ? res[o + 1] : 0.f;
      out[o] = v0 + r0;
      out[o + 1] = v1 + r1;
    }
  }
}

// ======== fused gate/up GEMV + SiLU, x staged in LDS (R5 proven) ========
__global__ __launch_bounds__(256) void gateup_lds(const float* __restrict__ gW,
                                                  const float* __restrict__ uW,
                                                  const float* __restrict__ x,
                                                  float* __restrict__ act) {
  int tid = threadIdx.x;
  int wid = tid >> 6, lane = tid & 63;
  int wave = (int)blockIdx.x * 4 + wid;
  int n0 = wave * 2;
  const f4v* g0 = (const f4v*)(gW + (size_t)n0 * HID_);
  const f4v* g1 = g0 + 1024;
  const f4v* u0 = (const f4v*)(uW + (size_t)n0 * HID_);
  const f4v* u1 = u0 + 1024;
  const f4v* xp = (const f4v*)x;
  __shared__ f4v xs[8][256];
  float ag0[8] = {}, ag1[8] = {}, au0[8] = {}, au1[8] = {};
  for (int ch = 0; ch < 4; ch++) {
    int base = ch * 256;
    if (ch) __syncthreads();
#pragma unroll
    for (int i = 0; i < 8; i++) xs[i][tid] = xp[(size_t)i * 1024 + base + tid];
    __syncthreads();
#pragma unroll
    for (int c = 0; c < 4; c++) {
      int r = lane + c * 64;
      f4v a0 = __builtin_nontemporal_load(g0 + base + r);
      f4v a1 = __builtin_nontemporal_load(g1 + base + r);
      f4v b0 = __builtin_nontemporal_load(u0 + base + r);
      f4v b1 = __builtin_nontemporal_load(u1 + base + r);
#pragma unroll
      for (int b = 0; b < 8; b++) {
        f4v xv = xs[b][r];
        ag0[b] += dot4v(a0, xv);
        ag1[b] += dot4v(a1, xv);
        au0[b] += dot4v(b0, xv);
        au1[b] += dot4v(b1, xv);
      }
    }
  }
#pragma unroll
  for (int b = 0; b < 8; b++) {
    float gv0 = wave_sum(ag0[b]);
    float gv1 = wave_sum(ag1[b]);
    float uv0 = wave_sum(au0[b]);
    float uv1 = wave_sum(au1[b]);
    if (lane == 0) {
      size_t o = (size_t)b * INTER_ + n0;
      act[o + 0] = gv0 / (1.f + __expf(-gv0)) * uv0;
      act[o + 1] = gv1 / (1.f + __expf(-gv1)) * uv1;
    }
  }
}

// ======== flash-decode attention partition (R5 proven) + folded last-block combine ========
__global__ __launch_bounds__(256) void attn_part_kernel(const float* __restrict__ qkv,
                                                        const float* __restrict__ kc,
                                                        const float* __restrict__ vc,
                                                        const int* __restrict__ pos,
                                                        float* __restrict__ partials,
                                                        int* __restrict__ counters,
                                                        float* __restrict__ ctx) {
  int blk = blockIdx.x;
  int part = blk & (NP_ - 1);
  int bh = blk >> 3;  // b*H + h
  int b = bh >> 5, h = bh & 31;
  int tid = threadIdx.x;
  int wid = tid >> 6, lane = tid & 63;
  int grp = lane >> 3, j = lane & 7;

  __shared__ __align__(16) float s_q[D_];
  __shared__ float s_m[4], s_l[4];
  __shared__ __align__(16) f4v s_acc[4][32];
  __shared__ int s_elect;

  const float* qraw = qkv + (size_t)b * (3 * HID_) + h * D_;
  if (tid < 64) {
    float p = (float)pos[b];
    float invf = __expf(-((float)tid * (1.0f / 64.0f)) * 9.210340371976184f);
    float ang = p * invf;
    float c = cosf(ang), s = sinf(ang);
    float q1 = qraw[tid], q2 = qraw[tid + 64];
    s_q[tid] = q1 * c - q2 * s;
    s_q[tid + 64] = q1 * s + q2 * c;
  }
  __syncthreads();

  f4v qf[4];
#pragma unroll
  for (int c = 0; c < 4; c++) qf[c] = ((const f4v*)s_q)[c * 8 + j];

  const float scale = 0.08838834764831845f;  // 1/sqrt(128)
  const size_t rstride = H_ * D_ / 4;        // 1024 f4 per L-row
  const f4v* kb = (const f4v*)kc + ((size_t)b * L_ * H_ + h) * (D_ / 4);
  const f4v* vb = (const f4v*)vc + ((size_t)b * L_ * H_ + h) * (D_ / 4);
  int base = part * (L_ / NP_) + wid * (L_ / NP_ / 4);

  float m = -1e30f, lsum = 0.f;
  f4v acc[4] = {};
#pragma unroll 2
  for (int it = 0; it < (L_ / NP_ / 4 / 8); it++) {
    int l = base + it * 8 + grp;
    const f4v* kp = kb + (size_t)l * rstride;
    const f4v* vp = vb + (size_t)l * rstride;
    f4v k0 = __builtin_nontemporal_load(kp + j);
    f4v k1 = __builtin_nontemporal_load(kp + 8 + j);
    f4v k2 = __builtin_nontemporal_load(kp + 16 + j);
    f4v k3 = __builtin_nontemporal_load(kp + 24 + j);
    f4v v0 = __builtin_nontemporal_load(vp + j);
    f4v v1 = __builtin_nontemporal_load(vp + 8 + j);
    f4v v2 = __builtin_nontemporal_load(vp + 16 + j);
    f4v v3 = __builtin_nontemporal_load(vp + 24 + j);
    float s = dot4v(k0, qf[0]) + dot4v(k1, qf[1]) + dot4v(k2, qf[2]) + dot4v(k3, qf[3]);
    s += __shfl_xor(s, 1, 64);
    s += __shfl_xor(s, 2, 64);
    s += __shfl_xor(s, 4, 64);
    s *= scale;
    // branch-free online softmax update
    float mn = fmaxf(m, s);
    float f = __expf(m - mn);
    float p = __expf(s - mn);
    m = mn;
    lsum = lsum * f + p;
    acc[0] = acc[0] * f + p * v0;
    acc[1] = acc[1] * f + p * v1;
    acc[2] = acc[2] * f + p * v2;
    acc[3] = acc[3] * f + p * v3;
  }

  // merge the 8 groups within the wave (butterfly over masks 8,16,32)
#pragma unroll
  for (int mask = 8; mask <= 32; mask <<= 1) {
    float m2 = __shfl_xor(m, mask, 64);
    float l2 = __shfl_xor(lsum, mask, 64);
    f4v a0 = shfl_xor4(acc[0], mask);
    f4v a1 = shfl_xor4(acc[1], mask);
    f4v a2 = shfl_xor4(acc[2], mask);
    f4v a3 = shfl_xor4(acc[3], mask);
    float mn = fmaxf(m, m2);
    float f1 = __expf(m - mn), f2 = __expf(m2 - mn);
    lsum = lsum * f1 + l2 * f2;
    acc[0] = acc[0] * f1 + a0 * f2;
    acc[1] = acc[1] * f1 + a1 * f2;
    acc[2] = acc[2] * f1 + a2 * f2;
    acc[3] = acc[3] * f1 + a3 * f2;
    m = mn;
  }
  if (lane < 8) {
#pragma unroll
    for (int c = 0; c < 4; c++) s_acc[wid][c * 8 + lane] = acc[c];
  }
  if (lane == 0) {
    s_m[wid] = m;
    s_l[wid] = lsum;
  }
  __syncthreads();
  if (tid < 32) {
    float gm = fmaxf(fmaxf(s_m[0], s_m[1]), fmaxf(s_m[2], s_m[3]));
    float f0 = __expf(s_m[0] - gm);
    float f1 = __expf(s_m[1] - gm);
    float f2 = __expf(s_m[2] - gm);
    float f3 = __expf(s_m[3] - gm);
    f4v a = s_acc[0][tid] * f0 + s_acc[1][tid] * f1 + s_acc[2][tid] * f2 + s_acc[3][tid] * f3;
    float* pout = partials + ((size_t)bh * NP_ + part) * PSTRIDE_;
    ((f4v*)pout)[tid] = a;
    if (tid == 0) {
      pout[128] = gm;
      pout[129] = s_l[0] * f0 + s_l[1] * f1 + s_l[2] * f2 + s_l[3] * f3;
    }
  }

  // ---- split-K fold: last finished block for this bh performs the combine ----
  __syncthreads();  // all partial stores issued block-wide
  if (tid == 0) {
    __threadfence();  // release: partial visible device-wide before count
    int old = atomicAdd(&counters[bh], 1);
    s_elect = (old == NP_ - 1) ? 1 : 0;
  }
  __syncthreads();
  if (s_elect) {
    __threadfence();  // acquire: make all producers' partials visible
    __shared__ float s_k2[D_], s_v2[D_];
    __shared__ float s_sn;
    const float* kraw = qraw + HID_;
    const float* vraw = qraw + 2 * HID_;
    if (tid < 64) {
      float p = (float)pos[b];
      float invf = __expf(-((float)tid * (1.0f / 64.0f)) * 9.210340371976184f);
      float ang = p * invf;
      float c = cosf(ang), s = sinf(ang);
      float k1 = kraw[tid], k2 = kraw[tid + 64];
      s_k2[tid] = k1 * c - k2 * s;
      s_k2[tid + 64] = k1 * s + k2 * c;
      s_v2[tid] = vraw[tid];
      s_v2[tid + 64] = vraw[tid + 64];
    }
    __syncthreads();
    if (tid < 64) {
      float a = s_q[tid] * s_k2[tid] + s_q[tid + 64] * s_k2[tid + 64];
      a = wave_sum(a);
      if (tid == 0) s_sn = a * scale;
    }
    __syncthreads();
    if (tid < D_) {
      float snew = s_sn;
      const float* p0 = partials + (size_t)bh * NP_ * PSTRIDE_;
      float gm = snew;
#pragma unroll
      for (int p = 0; p < NP_; p++) gm = fmaxf(gm, p0[p * PSTRIDE_ + 128]);
      float fn = __expf(snew - gm);
      float Lden = fn;
      float num = fn * s_v2[tid];
#pragma unroll
      for (int p = 0; p < NP_; p++) {
        float f = __expf(p0[p * PSTRIDE_ + 128] - gm);
        Lden += p0[p * PSTRIDE_ + 129] * f;
        num += p0[p * PSTRIDE_ + tid] * f;
      }
      ctx[(size_t)b * HID_ + h * D_ + tid] = num / Lden;
    }
  }
}

extern "C" void kernel_launch(void* const* d_in, const int* in_sizes, int n_in,
                              void* d_out, int out_size, void* d_ws, size_t ws_size,
                              hipStream_t stream) {
  (void)in_sizes; (void)n_in; (void)out_size; (void)ws_size;
  const float* hidden = (const float*)d_in[0];
  const float* kc     = (const float*)d_in[1];
  const float* vc     = (const float*)d_in[2];
  const float* w_pack = (const float*)d_in[3];
  const float* o_w    = (const float*)d_in[4];
  const float* gate_w = (const float*)d_in[5];
  const float* up_w   = (const float*)d_in[6];
  const float* down_w = (const float*)d_in[7];
  const float* ln1    = (const float*)d_in[8];
  const float* ln2    = (const float*)d_in[9];
  const int*   pos    = (const int*)d_in[10];
  float* out = (float*)d_out;
  float* ws  = (float*)d_ws;

  float* xn       = ws;            // 32768 (B*HID)
  float* qkv      = ws + 32768;    // 98304 (B*3*HID)
  float* ctx      = ws + 131072;   // 32768
  float* h1       = ws + 163840;   // 32768
  float* h2       = ws + 196608;   // 32768
  float* act      = ws + 229376;   // 88064 (B*INTER)
  float* partials = ws + 317440;   // B*H*NP_*PSTRIDE_ = 278528
  int*   counters = (int*)(ws + 317440 + 278528);  // 256 ints

  // 1. RMSNorm(hidden, ln1) -> xn   (block 0 also zeroes the attn counters)
  rmsnorm_kernel<<<B_, 1024, 0, stream>>>(hidden, ln1, xn, counters);
  // 2. qkv = xn @ w_pack.T   (12288 rows, 2 rows/wave -> 1536 blocks)
  gemv_lds<HID_><<<1536, 256, 0, stream>>>(w_pack, xn, nullptr, qkv, 3 * HID_);
  // 3. flash-decode partials + folded per-bh combine -> ctx
  attn_part_kernel<<<B_ * H_ * NP_, 256, 0, stream>>>(qkv, kc, vc, pos, partials, counters, ctx);
  // 4. h1 = hidden + ctx @ o_proj.T  (4096 rows, 2 rows/wave -> 512 blocks)
  gemv_lds<HID_><<<512, 256, 0, stream>>>(o_w, ctx, hidden, h1, HID_);
  // 5. RMSNorm(h1, ln2) -> h2
  rmsnorm_kernel<<<B_, 1024, 0, stream>>>(h1, ln2, h2, nullptr);
  // 6. act = silu(h2@gate.T) * (h2@up.T)   (11008 rows -> 1376 blocks)
  gateup_lds<<<1376, 256, 0, stream>>>(gate_w, up_w, h2, act);
  // 7. out = h1 + act @ down.T  (4096 rows, K=11008 -> 512 blocks)
  gemv_lds<INTER_><<<512, 256, 0, stream>>>(down_w, act, h1, out, HID_);
}

// Round 9
// 391.741 us; speedup vs baseline: 2.1070x; 2.1070x over previous
//
#include <hip/hip_runtime.h>
#include <math.h>

#define B_ 8
#define L_ 4096
#define H_ 32
#define D_ 128
#define HID_ 4096
#define INTER_ 11008
#define EPS_ 1e-6f
#define NP_ 8          // attention partitions over L
#define PSTRIDE_ 136   // floats per attention partial: 128 acc + m + l + pad

typedef float f4v __attribute__((ext_vector_type(4)));

__device__ __forceinline__ float dot4v(f4v a, f4v b) {
  f4v t = a * b;
  return t.x + t.y + t.z + t.w;
}
__device__ __forceinline__ float wave_sum(float v) {
#pragma unroll
  for (int m = 32; m >= 1; m >>= 1) v += __shfl_xor(v, m, 64);
  return v;
}
__device__ __forceinline__ f4v shfl_xor4(f4v v, int mask) {
  f4v r;
  r.x = __shfl_xor(v.x, mask, 64);
  r.y = __shfl_xor(v.y, mask, 64);
  r.z = __shfl_xor(v.z, mask, 64);
  r.w = __shfl_xor(v.w, mask, 64);
  return r;
}

// ---------------- RMSNorm: grid=B, block=1024 (R1/R3 proven) ----------------
__global__ __launch_bounds__(1024) void rmsnorm_kernel(const float* __restrict__ x,
                                                       const float* __restrict__ w,
                                                       float* __restrict__ out) {
  int b = blockIdx.x;
  const float4* xb = (const float4*)(x + (size_t)b * HID_);
  const float4* wp = (const float4*)w;
  float4* ob = (float4*)(out + (size_t)b * HID_);
  int tid = threadIdx.x;
  float4 v = xb[tid];
  float ss = v.x * v.x + v.y * v.y + v.z * v.z + v.w * v.w;
  ss = wave_sum(ss);
  __shared__ float red[16];
  int wid = tid >> 6, lane = tid & 63;
  if (lane == 0) red[wid] = ss;
  __syncthreads();
  float tot = 0.f;
#pragma unroll
  for (int i = 0; i < 16; i++) tot += red[i];
  float rs = rsqrtf(tot * (1.0f / (float)HID_) + EPS_);
  float4 wv = wp[tid];
  float4 o;
  o.x = v.x * rs * wv.x;
  o.y = v.y * rs * wv.y;
  o.z = v.z * rs * wv.z;
  o.w = v.w * rs * wv.w;
  ob[tid] = o;
}

// ======== GEMV with x staged in LDS (R5 proven) ========
template <int KD>
__global__ __launch_bounds__(256) void gemv_lds(const float* __restrict__ W,
                                                const float* __restrict__ x,
                                                const float* __restrict__ res,
                                                float* __restrict__ out, int ostride) {
  constexpr int NF4 = KD / 4;
  constexpr int NCH = (NF4 + 255) / 256;
  int tid = threadIdx.x;
  int wid = tid >> 6, lane = tid & 63;
  int wave = (int)blockIdx.x * 4 + wid;
  int n0 = wave * 2;
  const f4v* w0 = (const f4v*)(W + (size_t)n0 * KD);
  const f4v* w1 = w0 + NF4;
  const f4v* xp = (const f4v*)x;
  __shared__ f4v xs[8][256];
  float acc0[8] = {}, acc1[8] = {};
  for (int ch = 0; ch < NCH; ch++) {
    int base = ch * 256;
    int cnt = NF4 - base;
    if (cnt > 256) cnt = 256;
    if (ch) __syncthreads();  // protect previous chunk reads
    if (tid < cnt) {
#pragma unroll
      for (int i = 0; i < 8; i++) xs[i][tid] = xp[(size_t)i * NF4 + base + tid];
    }
    __syncthreads();
#pragma unroll
    for (int c = 0; c < 4; c++) {
      int r4 = lane + c * 64;
      if (r4 < cnt) {
        f4v a0 = __builtin_nontemporal_load(w0 + base + r4);
        f4v a1 = __builtin_nontemporal_load(w1 + base + r4);
#pragma unroll
        for (int b = 0; b < 8; b++) {
          f4v xv = xs[b][r4];
          acc0[b] += dot4v(a0, xv);
          acc1[b] += dot4v(a1, xv);
        }
      }
    }
  }
#pragma unroll
  for (int b = 0; b < 8; b++) {
    float v0 = wave_sum(acc0[b]);
    float v1 = wave_sum(acc1[b]);
    if (lane == 0) {
      size_t o = (size_t)b * ostride + n0;
      float r0 = res ? res[o] : 0.f;
      float r1 = res ? res[o + 1] : 0.f;
      out[o] = v0 + r0;
      out[o + 1] = v1 + r1;
    }
  }
}

// ======== fused gate/up GEMV + SiLU, x staged in LDS (R5 proven) ========
__global__ __launch_bounds__(256) void gateup_lds(const float* __restrict__ gW,
                                                  const float* __restrict__ uW,
                                                  const float* __restrict__ x,
                                                  float* __restrict__ act) {
  int tid = threadIdx.x;
  int wid = tid >> 6, lane = tid & 63;
  int wave = (int)blockIdx.x * 4 + wid;
  int n0 = wave * 2;
  const f4v* g0 = (const f4v*)(gW + (size_t)n0 * HID_);
  const f4v* g1 = g0 + 1024;
  const f4v* u0 = (const f4v*)(uW + (size_t)n0 * HID_);
  const f4v* u1 = u0 + 1024;
  const f4v* xp = (const f4v*)x;
  __shared__ f4v xs[8][256];
  float ag0[8] = {}, ag1[8] = {}, au0[8] = {}, au1[8] = {};
  for (int ch = 0; ch < 4; ch++) {
    int base = ch * 256;
    if (ch) __syncthreads();
#pragma unroll
    for (int i = 0; i < 8; i++) xs[i][tid] = xp[(size_t)i * 1024 + base + tid];
    __syncthreads();
#pragma unroll
    for (int c = 0; c < 4; c++) {
      int r = lane + c * 64;
      f4v a0 = __builtin_nontemporal_load(g0 + base + r);
      f4v a1 = __builtin_nontemporal_load(g1 + base + r);
      f4v b0 = __builtin_nontemporal_load(u0 + base + r);
      f4v b1 = __builtin_nontemporal_load(u1 + base + r);
#pragma unroll
      for (int b = 0; b < 8; b++) {
        f4v xv = xs[b][r];
        ag0[b] += dot4v(a0, xv);
        ag1[b] += dot4v(a1, xv);
        au0[b] += dot4v(b0, xv);
        au1[b] += dot4v(b1, xv);
      }
    }
  }
#pragma unroll
  for (int b = 0; b < 8; b++) {
    float gv0 = wave_sum(ag0[b]);
    float gv1 = wave_sum(ag1[b]);
    float uv0 = wave_sum(au0[b]);
    float uv1 = wave_sum(au1[b]);
    if (lane == 0) {
      size_t o = (size_t)b * INTER_ + n0;
      act[o + 0] = gv0 / (1.f + __expf(-gv0)) * uv0;
      act[o + 1] = gv1 / (1.f + __expf(-gv1)) * uv1;
    }
  }
}

// ======== flash-decode attention partition (R3/R5 proven) ========
__global__ __launch_bounds__(256) void attn_part_kernel(const float* __restrict__ qkv,
                                                        const float* __restrict__ kc,
                                                        const float* __restrict__ vc,
                                                        const int* __restrict__ pos,
                                                        float* __restrict__ partials) {
  int blk = blockIdx.x;
  int part = blk & (NP_ - 1);
  int bh = blk >> 3;  // b*H + h
  int b = bh >> 5, h = bh & 31;
  int tid = threadIdx.x;
  int wid = tid >> 6, lane = tid & 63;
  int grp = lane >> 3, j = lane & 7;

  __shared__ __align__(16) float s_q[D_];
  __shared__ float s_m[4], s_l[4];
  __shared__ __align__(16) f4v s_acc[4][32];

  const float* qraw = qkv + (size_t)b * (3 * HID_) + h * D_;
  if (tid < 64) {
    float p = (float)pos[b];
    float invf = __expf(-((float)tid * (1.0f / 64.0f)) * 9.210340371976184f);
    float ang = p * invf;
    float c = cosf(ang), s = sinf(ang);
    float q1 = qraw[tid], q2 = qraw[tid + 64];
    s_q[tid] = q1 * c - q2 * s;
    s_q[tid + 64] = q1 * s + q2 * c;
  }
  __syncthreads();

  f4v qf[4];
#pragma unroll
  for (int c = 0; c < 4; c++) qf[c] = ((const f4v*)s_q)[c * 8 + j];

  const float scale = 0.08838834764831845f;  // 1/sqrt(128)
  const size_t rstride = H_ * D_ / 4;        // 1024 f4 per L-row
  const f4v* kb = (const f4v*)kc + ((size_t)b * L_ * H_ + h) * (D_ / 4);
  const f4v* vb = (const f4v*)vc + ((size_t)b * L_ * H_ + h) * (D_ / 4);
  int base = part * (L_ / NP_) + wid * (L_ / NP_ / 4);

  float m = -1e30f, lsum = 0.f;
  f4v acc[4] = {};
#pragma unroll 2
  for (int it = 0; it < (L_ / NP_ / 4 / 8); it++) {
    int l = base + it * 8 + grp;
    const f4v* kp = kb + (size_t)l * rstride;
    const f4v* vp = vb + (size_t)l * rstride;
    f4v k0 = __builtin_nontemporal_load(kp + j);
    f4v k1 = __builtin_nontemporal_load(kp + 8 + j);
    f4v k2 = __builtin_nontemporal_load(kp + 16 + j);
    f4v k3 = __builtin_nontemporal_load(kp + 24 + j);
    f4v v0 = __builtin_nontemporal_load(vp + j);
    f4v v1 = __builtin_nontemporal_load(vp + 8 + j);
    f4v v2 = __builtin_nontemporal_load(vp + 16 + j);
    f4v v3 = __builtin_nontemporal_load(vp + 24 + j);
    float s = dot4v(k0, qf[0]) + dot4v(k1, qf[1]) + dot4v(k2, qf[2]) + dot4v(k3, qf[3]);
    s += __shfl_xor(s, 1, 64);
    s += __shfl_xor(s, 2, 64);
    s += __shfl_xor(s, 4, 64);
    s *= scale;
    // branch-free online softmax update (single basic block -> pipelineable)
    float mn = fmaxf(m, s);
    float f = __expf(m - mn);
    float p = __expf(s - mn);
    m = mn;
    lsum = lsum * f + p;
    acc[0] = acc[0] * f + p * v0;
    acc[1] = acc[1] * f + p * v1;
    acc[2] = acc[2] * f + p * v2;
    acc[3] = acc[3] * f + p * v3;
  }

  // merge the 8 groups within the wave (butterfly over masks 8,16,32)
#pragma unroll
  for (int mask = 8; mask <= 32; mask <<= 1) {
    float m2 = __shfl_xor(m, mask, 64);
    float l2 = __shfl_xor(lsum, mask, 64);
    f4v a0 = shfl_xor4(acc[0], mask);
    f4v a1 = shfl_xor4(acc[1], mask);
    f4v a2 = shfl_xor4(acc[2], mask);
    f4v a3 = shfl_xor4(acc[3], mask);
    float mn = fmaxf(m, m2);
    float f1 = __expf(m - mn), f2 = __expf(m2 - mn);
    lsum = lsum * f1 + l2 * f2;
    acc[0] = acc[0] * f1 + a0 * f2;
    acc[1] = acc[1] * f1 + a1 * f2;
    acc[2] = acc[2] * f1 + a2 * f2;
    acc[3] = acc[3] * f1 + a3 * f2;
    m = mn;
  }
  if (lane < 8) {
#pragma unroll
    for (int c = 0; c < 4; c++) s_acc[wid][c * 8 + lane] = acc[c];
  }
  if (lane == 0) {
    s_m[wid] = m;
    s_l[wid] = lsum;
  }
  __syncthreads();
  if (tid < 32) {
    float gm = fmaxf(fmaxf(s_m[0], s_m[1]), fmaxf(s_m[2], s_m[3]));
    float f0 = __expf(s_m[0] - gm);
    float f1 = __expf(s_m[1] - gm);
    float f2 = __expf(s_m[2] - gm);
    float f3 = __expf(s_m[3] - gm);
    f4v a = s_acc[0][tid] * f0 + s_acc[1][tid] * f1 + s_acc[2][tid] * f2 + s_acc[3][tid] * f3;
    float* pout = partials + ((size_t)bh * NP_ + part) * PSTRIDE_;
    ((f4v*)pout)[tid] = a;
    if (tid == 0) {
      pout[128] = gm;
      pout[129] = s_l[0] * f0 + s_l[1] * f1 + s_l[2] * f2 + s_l[3] * f3;
    }
  }
}

// ======== attention combine (R3/R5 proven) ========
__global__ __launch_bounds__(128) void attn_combine_kernel(const float* __restrict__ qkv,
                                                           const int* __restrict__ pos,
                                                           const float* __restrict__ partials,
                                                           float* __restrict__ ctx) {
  int bh = blockIdx.x;
  int b = bh >> 5, h = bh & 31;
  int tid = threadIdx.x;

  __shared__ float s_q[D_], s_k[D_], s_v[D_];
  __shared__ float s_snew;

  const float* qraw = qkv + (size_t)b * (3 * HID_) + h * D_;
  const float* kraw = qraw + HID_;
  const float* vraw = qraw + 2 * HID_;
  if (tid < 64) {
    float p = (float)pos[b];
    float invf = __expf(-((float)tid * (1.0f / 64.0f)) * 9.210340371976184f);
    float ang = p * invf;
    float c = cosf(ang), s = sinf(ang);
    float q1 = qraw[tid], q2 = qraw[tid + 64];
    s_q[tid] = q1 * c - q2 * s;
    s_q[tid + 64] = q1 * s + q2 * c;
    float k1 = kraw[tid], k2 = kraw[tid + 64];
    s_k[tid] = k1 * c - k2 * s;
    s_k[tid + 64] = k1 * s + k2 * c;
  } else {
    int d = tid - 64;
    s_v[d] = vraw[d];
    s_v[d + 64] = vraw[d + 64];
  }
  __syncthreads();
  if (tid < 64) {
    float a = s_q[tid] * s_k[tid] + s_q[tid + 64] * s_k[tid + 64];
    a = wave_sum(a);
    if (tid == 0) s_snew = a * 0.08838834764831845f;
  }
  __syncthreads();
  float snew = s_snew;

  const float* p0 = partials + (size_t)bh * NP_ * PSTRIDE_;
  float gm = snew;
#pragma unroll
  for (int p = 0; p < NP_; p++) gm = fmaxf(gm, p0[p * PSTRIDE_ + 128]);
  float fn = __expf(snew - gm);
  float L = fn;
  float num = fn * s_v[tid];
#pragma unroll
  for (int p = 0; p < NP_; p++) {
    float f = __expf(p0[p * PSTRIDE_ + 128] - gm);
    L += p0[p * PSTRIDE_ + 129] * f;
    num += p0[p * PSTRIDE_ + tid] * f;
  }
  ctx[(size_t)b * HID_ + h * D_ + tid] = num / L;
}

extern "C" void kernel_launch(void* const* d_in, const int* in_sizes, int n_in,
                              void* d_out, int out_size, void* d_ws, size_t ws_size,
                              hipStream_t stream) {
  (void)in_sizes; (void)n_in; (void)out_size; (void)ws_size;
  const float* hidden = (const float*)d_in[0];
  const float* kc     = (const float*)d_in[1];
  const float* vc     = (const float*)d_in[2];
  const float* w_pack = (const float*)d_in[3];
  const float* o_w    = (const float*)d_in[4];
  const float* gate_w = (const float*)d_in[5];
  const float* up_w   = (const float*)d_in[6];
  const float* down_w = (const float*)d_in[7];
  const float* ln1    = (const float*)d_in[8];
  const float* ln2    = (const float*)d_in[9];
  const int*   pos    = (const int*)d_in[10];
  float* out = (float*)d_out;
  float* ws  = (float*)d_ws;

  float* xn       = ws;            // 32768 (B*HID)
  float* qkv      = ws + 32768;    // 98304 (B*3*HID)
  float* ctx      = ws + 131072;   // 32768
  float* h1       = ws + 163840;   // 32768
  float* h2       = ws + 196608;   // 32768
  float* act      = ws + 229376;   // 88064 (B*INTER)
  float* partials = ws + 317440;   // B*H*NP_*PSTRIDE_ = 278528

  // 1. RMSNorm(hidden, ln1) -> xn
  rmsnorm_kernel<<<B_, 1024, 0, stream>>>(hidden, ln1, xn);
  // 2. qkv = xn @ w_pack.T   (12288 rows, 2 rows/wave -> 1536 blocks)
  gemv_lds<HID_><<<1536, 256, 0, stream>>>(w_pack, xn, nullptr, qkv, 3 * HID_);
  // 3a. flash-decode partials over the KV cache (NP_=8 -> 2048 blocks)
  attn_part_kernel<<<B_ * H_ * NP_, 256, 0, stream>>>(qkv, kc, vc, pos, partials);
  // 3b. combine partials + new token -> ctx
  attn_combine_kernel<<<B_ * H_, 128, 0, stream>>>(qkv, pos, partials, ctx);
  // 4. h1 = hidden + ctx @ o_proj.T  (4096 rows, 2 rows/wave -> 512 blocks)
  gemv_lds<HID_><<<512, 256, 0, stream>>>(o_w, ctx, hidden, h1, HID_);
  // 5. RMSNorm(h1, ln2) -> h2
  rmsnorm_kernel<<<B_, 1024, 0, stream>>>(h1, ln2, h2);
  // 6. act = silu(h2@gate.T) * (h2@up.T)   (11008 rows -> 1376 blocks)
  gateup_lds<<<1376, 256, 0, stream>>>(gate_w, up_w, h2, act);
  // 7. out = h1 + act @ down.T  (4096 rows, K=11008 -> 512 blocks)
  gemv_lds<INTER_><<<512, 256, 0, stream>>>(down_w, act, h1, out, HID_);
}